// Round 12
// baseline (97.514 us; speedup 1.0000x reference)
//
#include <hip/hip_runtime.h>
#include <hip/hip_bf16.h>

// memristor_dense: y[b,j] = sum_i A[i,2j]*2^(e[i,2j]*l[b,i]) - A[i,2j+1]*2^(e[i,2j+1]*l[b,i])
//   A[i,j] = 0.5*|w[i,j]| + max_w/18, e = log2(n_param)+1, l = log2(2*clip(x))
// shapes: x(128,1024), w_pos/w_neg(1024,512), b_pos/b_neg(512), n_param(1025,1024)
//
// R11 -> R12: single change -- re-add __launch_bounds__(256, 8) to the main
// kernel (keeps R11's aligned __shared__ float4 sL tile; R10's crash is
// attributed to its misaligned (float4*) cast of a 4B-aligned float array,
// fixed in R11). Rationale: issue model says ~10-12us; measured ~20.6us = 2x.
// Grid 2048 = exactly 8 blocks/CU (one generation) -- if the compiler used
// >64 VGPRs without the bound, only 6-7 blocks are resident and the kernel
// runs as 2 generations = the observed 2x. Pinning 8 waves/EU (VGPR<=64)
// restores single-generation execution.

#define LOG2F(v)  __builtin_amdgcn_logf(v)    // v_log_f32: log2(x)
#define EXP2F(v)  __builtin_amdgcn_exp2f(v)   // v_exp_f32: 2^x

#define NJ 16        // jpairs per block
#define NB 64        // batch rows per block (4 per thread)
#define KI 32        // i-rows per block (one chunk, z-split 32)
#define SLS4 17      // sL k-row stride in float4 (16 rows-of-4 + pad)

__global__ __launch_bounds__(256) void setup_kernel(
    const float* __restrict__ w_pos, const float* __restrict__ w_neg,
    const float* __restrict__ b_pos, const float* __restrict__ b_neg,
    float* __restrict__ y, int* __restrict__ ws) {
  const int t = threadIdx.x, blk = blockIdx.x;
  // zero d_out: 16384 float4 over 256 blocks = 64 per block
  float4* y4 = (float4*)y;
  if (t < 64) y4[blk * 64 + t] = make_float4(0.f, 0.f, 0.f, 0.f);
  // |w| max partial: each array 131072 float4 -> 512 per block -> 2 per thread
  const float4* wp4 = (const float4*)w_pos;
  const float4* wn4 = (const float4*)w_neg;
  float m = 0.0f;
  #pragma unroll
  for (int r = 0; r < 2; ++r) {
    int i = blk * 512 + r * 256 + t;
    float4 a = wp4[i], b = wn4[i];
    m = fmaxf(m, fmaxf(fmaxf(fabsf(a.x), fabsf(a.y)), fmaxf(fabsf(a.z), fabsf(a.w))));
    m = fmaxf(m, fmaxf(fmaxf(fabsf(b.x), fabsf(b.y)), fmaxf(fabsf(b.z), fabsf(b.w))));
  }
  if (blk == 0) {
    m = fmaxf(m, fmaxf(fabsf(b_pos[t]), fabsf(b_pos[t + 256])));
    m = fmaxf(m, fmaxf(fabsf(b_neg[t]), fabsf(b_neg[t + 256])));
  }
  #pragma unroll
  for (int off = 32; off > 0; off >>= 1)
    m = fmaxf(m, __shfl_down(m, off, 64));
  __shared__ float sm[4];
  int lane = t & 63, wv = t >> 6;
  if (lane == 0) sm[wv] = m;
  __syncthreads();
  if (t == 0) {
    m = fmaxf(fmaxf(sm[0], sm[1]), fmaxf(sm[2], sm[3]));
    // positive-float bits compare correctly as int; poisoned 0xAAAAAAAA is
    // negative as int, so ws needs no initialization.
    atomicMax(ws, __float_as_int(m));
  }
}

__global__ __launch_bounds__(256, 8) void memristor_kernel(
    const float* __restrict__ x, const float* __restrict__ w_pos,
    const float* __restrict__ w_neg, const float* __restrict__ b_pos,
    const float* __restrict__ b_neg, const float* __restrict__ n_param,
    const float* __restrict__ ws, float* __restrict__ y) {
  __shared__ float4 sP[KI * NJ];     // [k][jj] = {A0,E0,A1,E1}, k-major
  __shared__ float4 sL4[KI * SLS4];  // [k][row/4], k-major; 16B-aligned by type

  const float mw = __int_as_float(((const int*)ws)[0]);
  const float c0 = mw * (0.05f / 0.9f);   // G_MIN*V_REF/(K_V*k_G) = max_w/18

  const int j0 = blockIdx.x * NJ;   // 32 j-tiles
  const int b0 = blockIdx.y * NB;   // 2 b-tiles
  const int zt = blockIdx.z;        // 32-way i-split: rows [zt*32, zt*32+32)
  const int i0 = zt * KI;
  const int t  = threadIdx.x;
  const int jj = t & 15;
  const int bq = t >> 4;            // [0,16): rows 4bq..4bq+3

  const float2* np2 = (const float2*)n_param;

  // stage params k-major: 32 i x 16 j = 512 entries, 2 per thread
  #pragma unroll
  for (int r = 0; r < 2; ++r) {
    int il = r * 16 + (t >> 4);
    int jl = t & 15;
    int gi = i0 + il;
    float wp = w_pos[gi * 512 + j0 + jl];
    float wn = w_neg[gi * 512 + j0 + jl];
    float2 np = np2[gi * 512 + j0 + jl];
    sP[il * NJ + jl] = make_float4(
        fmaf(0.5f, fabsf(wp), c0), LOG2F(np.x) + 1.0f,
        fmaf(0.5f, fabsf(wn), c0), LOG2F(np.y) + 1.0f);
  }
  // stage x transposed: 64 rows x 32 k; coalesced float4 reads, scalar writes
  {
    float* sL = (float*)sL4;
    const float4* x4 = (const float4*)x;
    #pragma unroll
    for (int r = 0; r < 2; ++r) {
      int row = r * 32 + (t >> 3);
      int k4  = t & 7;
      float4 v = x4[(b0 + row) * 256 + zt * 8 + k4];
      v.x = fminf(fmaxf(v.x, 0.0f), 1.0f);
      v.y = fminf(fmaxf(v.y, 0.0f), 1.0f);
      v.z = fminf(fmaxf(v.z, 0.0f), 1.0f);
      v.w = fminf(fmaxf(v.w, 0.0f), 1.0f);
      sL[(4 * k4 + 0) * (4 * SLS4) + row] = LOG2F(2.0f * v.x);
      sL[(4 * k4 + 1) * (4 * SLS4) + row] = LOG2F(2.0f * v.y);
      sL[(4 * k4 + 2) * (4 * SLS4) + row] = LOG2F(2.0f * v.z);
      sL[(4 * k4 + 3) * (4 * SLS4) + row] = LOG2F(2.0f * v.w);
    }
  }
  __syncthreads();

  float a0 = 0.0f, a1 = 0.0f, a2 = 0.0f, a3 = 0.0f;
  #pragma unroll 4
  for (int k = 0; k < KI; ++k) {
    float4 p = sP[k * NJ + jj];            // one b128, 16 addrs, 2-way banks
    float4 l = sL4[k * SLS4 + bq];         // one b128, 4 addrs, conflict-free
    a0 = fmaf(p.x, EXP2F(p.y * l.x), fmaf(-p.z, EXP2F(p.w * l.x), a0));
    a1 = fmaf(p.x, EXP2F(p.y * l.y), fmaf(-p.z, EXP2F(p.w * l.y), a1));
    a2 = fmaf(p.x, EXP2F(p.y * l.z), fmaf(-p.z, EXP2F(p.w * l.z), a2));
    a3 = fmaf(p.x, EXP2F(p.y * l.w), fmaf(-p.z, EXP2F(p.w * l.w), a3));
  }

  if (zt == 31) {
    // bias row i = 1024: inp = 1 -> vr = 2 -> 2^e; same for every b row
    int jg = j0 + jj;
    float2 np = np2[1024 * 512 + jg];
    float p0 = fmaf(0.5f, fabsf(b_pos[jg]), c0);
    float p1 = fmaf(0.5f, fabsf(b_neg[jg]), c0);
    float bias = p0 * EXP2F(LOG2F(np.x) + 1.0f) - p1 * EXP2F(LOG2F(np.y) + 1.0f);
    a0 += bias; a1 += bias; a2 += bias; a3 += bias;
  }

  const int row0 = b0 + 4 * bq;
  atomicAdd(&y[(row0 + 0) * 512 + j0 + jj], a0);
  atomicAdd(&y[(row0 + 1) * 512 + j0 + jj], a1);
  atomicAdd(&y[(row0 + 2) * 512 + j0 + jj], a2);
  atomicAdd(&y[(row0 + 3) * 512 + j0 + jj], a3);
}

extern "C" void kernel_launch(void* const* d_in, const int* in_sizes, int n_in,
                              void* d_out, int out_size, void* d_ws, size_t ws_size,
                              hipStream_t stream) {
  const float* x       = (const float*)d_in[0];
  const float* w_pos   = (const float*)d_in[1];
  const float* w_neg   = (const float*)d_in[2];
  const float* b_pos   = (const float*)d_in[3];
  const float* b_neg   = (const float*)d_in[4];
  const float* n_param = (const float*)d_in[5];
  float* y   = (float*)d_out;

  setup_kernel<<<dim3(256), dim3(256), 0, stream>>>(
      w_pos, w_neg, b_pos, b_neg, y, (int*)d_ws);

  memristor_kernel<<<dim3(32, 2, 32), dim3(256), 0, stream>>>(
      x, w_pos, w_neg, b_pos, b_neg, n_param, (const float*)d_ws, y);
}

// Round 13
// 87.477 us; speedup vs baseline: 1.1147x; 1.1147x over previous
//
#include <hip/hip_runtime.h>
#include <hip/hip_bf16.h>

// memristor_dense: y[b,j] = sum_i A[i,2j]*2^(e[i,2j]*l[b,i]) - A[i,2j+1]*2^(e[i,2j+1]*l[b,i])
//   A[i,j] = 0.5*|w[i,j]| + max_w/18, e = log2(n_param)+1, l = log2(2*clip(x))
// shapes: x(128,1024), w_pos/w_neg(1024,512), b_pos/b_neg(512), n_param(1025,1024)
//
// R12 -> R13: revert launch_bounds (R12: forced VGPR<=64 -> spills, 97.5us).
// Single change vs R11: split the param tile into two float2 arrays sPa/sPb.
// R11's sP b128 read hit 16 distinct float4 = 64 bank-slots = 2-way conflict
// (~24 cyc); two b64 reads over 16 addrs x 8B = exactly 32 banks each are
// conflict-free (~6 cyc each). sL read stays: 4 distinct addrs/wave, 16-way
// broadcast, free. Model: LDS/wave-iter 36 -> 24 cyc -> main ~20.6 -> ~14us.

#define LOG2F(v)  __builtin_amdgcn_logf(v)    // v_log_f32: log2(x)
#define EXP2F(v)  __builtin_amdgcn_exp2f(v)   // v_exp_f32: 2^x

#define NJ 16        // jpairs per block
#define NB 64        // batch rows per block (4 per thread)
#define KI 32        // i-rows per block (one chunk, z-split 32)
#define SLS4 17      // sL k-row stride in float4 (16 rows-of-4 + pad)

__global__ __launch_bounds__(256) void setup_kernel(
    const float* __restrict__ w_pos, const float* __restrict__ w_neg,
    const float* __restrict__ b_pos, const float* __restrict__ b_neg,
    float* __restrict__ y, int* __restrict__ ws) {
  const int t = threadIdx.x, blk = blockIdx.x;
  // zero d_out: 16384 float4 over 256 blocks = 64 per block
  float4* y4 = (float4*)y;
  if (t < 64) y4[blk * 64 + t] = make_float4(0.f, 0.f, 0.f, 0.f);
  // |w| max partial: each array 131072 float4 -> 512 per block -> 2 per thread
  const float4* wp4 = (const float4*)w_pos;
  const float4* wn4 = (const float4*)w_neg;
  float m = 0.0f;
  #pragma unroll
  for (int r = 0; r < 2; ++r) {
    int i = blk * 512 + r * 256 + t;
    float4 a = wp4[i], b = wn4[i];
    m = fmaxf(m, fmaxf(fmaxf(fabsf(a.x), fabsf(a.y)), fmaxf(fabsf(a.z), fabsf(a.w))));
    m = fmaxf(m, fmaxf(fmaxf(fabsf(b.x), fabsf(b.y)), fmaxf(fabsf(b.z), fabsf(b.w))));
  }
  if (blk == 0) {
    m = fmaxf(m, fmaxf(fabsf(b_pos[t]), fabsf(b_pos[t + 256])));
    m = fmaxf(m, fmaxf(fabsf(b_neg[t]), fabsf(b_neg[t + 256])));
  }
  #pragma unroll
  for (int off = 32; off > 0; off >>= 1)
    m = fmaxf(m, __shfl_down(m, off, 64));
  __shared__ float sm[4];
  int lane = t & 63, wv = t >> 6;
  if (lane == 0) sm[wv] = m;
  __syncthreads();
  if (t == 0) {
    m = fmaxf(fmaxf(sm[0], sm[1]), fmaxf(sm[2], sm[3]));
    // positive-float bits compare correctly as int; poisoned 0xAAAAAAAA is
    // negative as int, so ws needs no initialization.
    atomicMax(ws, __float_as_int(m));
  }
}

__global__ __launch_bounds__(256) void memristor_kernel(
    const float* __restrict__ x, const float* __restrict__ w_pos,
    const float* __restrict__ w_neg, const float* __restrict__ b_pos,
    const float* __restrict__ b_neg, const float* __restrict__ n_param,
    const float* __restrict__ ws, float* __restrict__ y) {
  __shared__ float2 sPa[KI * NJ];    // [k][jj] = {A0,E0}: 16 addrs x 8B = 32 banks, conflict-free
  __shared__ float2 sPb[KI * NJ];    // [k][jj] = {A1,E1}
  __shared__ float4 sL4[KI * SLS4];  // [k][row/4]; 4 addrs/wave, broadcast, free

  const float mw = __int_as_float(((const int*)ws)[0]);
  const float c0 = mw * (0.05f / 0.9f);   // G_MIN*V_REF/(K_V*k_G) = max_w/18

  const int j0 = blockIdx.x * NJ;   // 32 j-tiles
  const int b0 = blockIdx.y * NB;   // 2 b-tiles
  const int zt = blockIdx.z;        // 32-way i-split: rows [zt*32, zt*32+32)
  const int i0 = zt * KI;
  const int t  = threadIdx.x;
  const int jj = t & 15;
  const int bq = t >> 4;            // [0,16): rows 4bq..4bq+3

  const float2* np2 = (const float2*)n_param;

  // stage params k-major: 32 i x 16 j = 512 entries, 2 per thread
  #pragma unroll
  for (int r = 0; r < 2; ++r) {
    int il = r * 16 + (t >> 4);
    int jl = t & 15;
    int gi = i0 + il;
    float wp = w_pos[gi * 512 + j0 + jl];
    float wn = w_neg[gi * 512 + j0 + jl];
    float2 np = np2[gi * 512 + j0 + jl];
    sPa[il * NJ + jl] = make_float2(fmaf(0.5f, fabsf(wp), c0), LOG2F(np.x) + 1.0f);
    sPb[il * NJ + jl] = make_float2(fmaf(0.5f, fabsf(wn), c0), LOG2F(np.y) + 1.0f);
  }
  // stage x transposed: 64 rows x 32 k; coalesced float4 reads, scalar writes
  {
    float* sL = (float*)sL4;
    const float4* x4 = (const float4*)x;
    #pragma unroll
    for (int r = 0; r < 2; ++r) {
      int row = r * 32 + (t >> 3);
      int k4  = t & 7;
      float4 v = x4[(b0 + row) * 256 + zt * 8 + k4];
      v.x = fminf(fmaxf(v.x, 0.0f), 1.0f);
      v.y = fminf(fmaxf(v.y, 0.0f), 1.0f);
      v.z = fminf(fmaxf(v.z, 0.0f), 1.0f);
      v.w = fminf(fmaxf(v.w, 0.0f), 1.0f);
      sL[(4 * k4 + 0) * (4 * SLS4) + row] = LOG2F(2.0f * v.x);
      sL[(4 * k4 + 1) * (4 * SLS4) + row] = LOG2F(2.0f * v.y);
      sL[(4 * k4 + 2) * (4 * SLS4) + row] = LOG2F(2.0f * v.z);
      sL[(4 * k4 + 3) * (4 * SLS4) + row] = LOG2F(2.0f * v.w);
    }
  }
  __syncthreads();

  float a0 = 0.0f, a1 = 0.0f, a2 = 0.0f, a3 = 0.0f;
  #pragma unroll 4
  for (int k = 0; k < KI; ++k) {
    float2 pa = sPa[k * NJ + jj];          // b64, conflict-free
    float2 pb = sPb[k * NJ + jj];          // b64, conflict-free
    float4 l  = sL4[k * SLS4 + bq];        // b128, 4 addrs, broadcast
    a0 = fmaf(pa.x, EXP2F(pa.y * l.x), fmaf(-pb.x, EXP2F(pb.y * l.x), a0));
    a1 = fmaf(pa.x, EXP2F(pa.y * l.y), fmaf(-pb.x, EXP2F(pb.y * l.y), a1));
    a2 = fmaf(pa.x, EXP2F(pa.y * l.z), fmaf(-pb.x, EXP2F(pb.y * l.z), a2));
    a3 = fmaf(pa.x, EXP2F(pa.y * l.w), fmaf(-pb.x, EXP2F(pb.y * l.w), a3));
  }

  if (zt == 31) {
    // bias row i = 1024: inp = 1 -> vr = 2 -> 2^e; same for every b row
    int jg = j0 + jj;
    float2 np = np2[1024 * 512 + jg];
    float p0 = fmaf(0.5f, fabsf(b_pos[jg]), c0);
    float p1 = fmaf(0.5f, fabsf(b_neg[jg]), c0);
    float bias = p0 * EXP2F(LOG2F(np.x) + 1.0f) - p1 * EXP2F(LOG2F(np.y) + 1.0f);
    a0 += bias; a1 += bias; a2 += bias; a3 += bias;
  }

  const int row0 = b0 + 4 * bq;
  atomicAdd(&y[(row0 + 0) * 512 + j0 + jj], a0);
  atomicAdd(&y[(row0 + 1) * 512 + j0 + jj], a1);
  atomicAdd(&y[(row0 + 2) * 512 + j0 + jj], a2);
  atomicAdd(&y[(row0 + 3) * 512 + j0 + jj], a3);
}

extern "C" void kernel_launch(void* const* d_in, const int* in_sizes, int n_in,
                              void* d_out, int out_size, void* d_ws, size_t ws_size,
                              hipStream_t stream) {
  const float* x       = (const float*)d_in[0];
  const float* w_pos   = (const float*)d_in[1];
  const float* w_neg   = (const float*)d_in[2];
  const float* b_pos   = (const float*)d_in[3];
  const float* b_neg   = (const float*)d_in[4];
  const float* n_param = (const float*)d_in[5];
  float* y   = (float*)d_out;

  setup_kernel<<<dim3(256), dim3(256), 0, stream>>>(
      w_pos, w_neg, b_pos, b_neg, y, (int*)d_ws);

  memristor_kernel<<<dim3(32, 2, 32), dim3(256), 0, stream>>>(
      x, w_pos, w_neg, b_pos, b_neg, n_param, (const float*)d_ws, y);
}